// Round 10
// baseline (144.818 us; speedup 1.0000x reference)
//
#include <hip/hip_runtime.h>
#include <hip/hip_bf16.h>

// RuleGraphConvLayer R10: LDS holds the FINAL bf16 A-matrix (MFMA layout),
// built during the two staging phases; compute phase is pure ds_read+MFMA.
// K slots: [0..80] self(raw), [81..95] pad(B=0), [96..176] comb, [177..191] pad.
// Dead nodes (sel==0): cs=0 kills comb; self part masked at the store.
constexpr int kNodes = 262144;
constexpr int NC  = 103;   // feature columns
constexpr int F   = 81;    // used features
constexpr int OC  = 128;   // output channels
constexpr int NKS = 6;     // 6*32 = 192 K slots
constexpr int NPB = 64;    // nodes per block
constexpr int THREADS = 256;
constexpr int AST = 200;   // A-row stride in ushorts (400B: b128-aligned, even banks)

typedef __attribute__((ext_vector_type(8))) short bf16x8;
typedef __attribute__((ext_vector_type(4))) float f32x4;

__device__ inline ushort f2bf(float f) {
  uint u = __float_as_uint(f);
  return (ushort)((u + 0x7fffu + ((u >> 16) & 1u)) >> 16);  // RNE
}
__device__ inline uint pk2(float a, float b) {
  ushort ua = __bfloat16_as_ushort(__float2bfloat16(a));
  ushort ub = __bfloat16_as_ushort(__float2bfloat16(b));
  return (uint)ua | ((uint)ub << 16);
}

// B table in fragment order: wf[ks][ct][lane] = 8 bf16.
// B[k][c]: k = ks*32 + (lane>>4)*8 + i, c = ct*16 + (lane&15).
// Rows: k<81 -> w_s[k]; 96<=k<177 -> w_n[k-96]; else 0.
__global__ __launch_bounds__(256)
void prep_w(const float* __restrict__ w_s, const float* __restrict__ w_n,
            ushort* __restrict__ wf) {
  int t = blockIdx.x * 256 + threadIdx.x;
  if (t >= NKS * 8 * 64) return;
  int l  = t & 63;
  int ct = (t >> 6) & 7;
  int ks = t >> 9;
  int c  = ct * 16 + (l & 15);
  int kb = ks * 32 + ((l >> 4) << 3);
  union { ushort u[8]; int4 v; } o;
  #pragma unroll
  for (int i = 0; i < 8; ++i) {
    int k = kb + i;
    float f = 0.f;
    if (k < F)                      f = w_s[k * OC + c];
    else if (k >= 96 && k < 96 + F) f = w_n[(k - 96) * OC + c];
    o.u[i] = f2bf(f);
  }
  ((int4*)wf)[t] = o.v;
}

__global__ __launch_bounds__(THREADS, 4)
void rgc_v10(const float* __restrict__ feat, const ushort* __restrict__ wf,
             float* __restrict__ out) {
  __shared__ __align__(16) ushort a_bf[NPB * AST];  // 25600 B
  __shared__ int   s_sel[NPB];
  __shared__ float s_cs[NPB];

  const int tid = threadIdx.x;
  const int w   = tid >> 6;
  const int l   = tid & 63;
  const long base = (long)blockIdx.x * NPB;

  // ---- Hoisted B fragments: wave w owns ct = {w, w+4} (12 x 16B, once).
  const bf16x8* wfv = (const bf16x8*)wf;
  bf16x8 bA[NKS], bB[NKS];
  #pragma unroll
  for (int ks = 0; ks < NKS; ++ks) {
    bA[ks] = wfv[(ks * 8 + w)     * 64 + l];
    bB[ks] = wfv[(ks * 8 + w + 4) * 64 + l];
  }

  // ---- P1: self staging (raw bf16, slots [0..95]) + per-node meta.
  // Meta spread across waves: lanes 0..15 of wave w handle nodes w*16..w*16+15.
  if (l < 16) {
    const int n = w * 16 + l;
    const float* row = feat + (base + n) * NC;
    float f0 = row[F], f1 = row[F + 1];
    int i0 = (int)f0, i1 = (int)f1;
    int sel = (i1 != 0) ? i1 : i0;          // alive <=> sel != 0
    const float* nr = feat + (long)sel * NC;
    float dx = row[0] - nr[0];
    float dy = row[1] - nr[1];
    float dz = row[2] - nr[2];
    float d2 = dx * dx + dy * dy + dz * dz;
    float alive = (sel != 0) ? 1.f : 0.f;
    s_sel[n] = sel;
    s_cs[n]  = alive * ((d2 > 0.f) ? (1.f / d2) : 10000.f);
  }
  #pragma unroll
  for (int j = 0; j < 12; ++j) {
    int v  = tid + j * THREADS;        // 0..3071
    int n  = v / 48;
    int kp = (v - n * 48) * 2;         // 0,2,..,94 (48 threads cover a row)
    const float* sr = feat + (base + n) * NC + kp;
    float x0 = sr[0], x1 = sr[1];
    *(uint*)&a_bf[n * AST + kp] = pk2(x0, x1);
  }
  __syncthreads();

  // ---- P2: comb staging (slots [96..191]); gather coalesced within rows.
  #pragma unroll
  for (int j = 0; j < 12; ++j) {
    int v  = tid + j * THREADS;
    int n  = v / 48;
    int kp = (v - n * 48) * 2;
    const float* nr = feat + (long)s_sel[n] * NC + kp;
    const float* sr = feat + (base + n) * NC + kp;   // L1/L2-hot (read in P1)
    float cs = s_cs[n];
    float nv0 = nr[0], nv1 = nr[1];
    float sv0 = sr[0], sv1 = sr[1];
    float y0 = (nv0 + ((kp     < 3) ? 0.f : sv0)) * cs;  // comb kk<3: nei only
    float y1 = (nv1 + ((kp + 1 < 3) ? 0.f : sv1)) * cs;
    *(uint*)&a_bf[n * AST + 96 + kp] = pk2(y0, y1);
  }
  __syncthreads();

  // ---- P3: pure MFMA. Wave w: all 4 node-tiles x ct {w, w+4}.
  const int q    = l >> 4;
  const int lrow = l & 15;
  const int col  = l & 15;

  #pragma unroll
  for (int nt = 0; nt < 4; ++nt) {
    const ushort* ap = a_bf + (nt * 16 + lrow) * AST + q * 8;
    bf16x8 af[NKS];
    #pragma unroll
    for (int ks = 0; ks < NKS; ++ks) af[ks] = *(const bf16x8*)(ap + ks * 32);

    f32x4 a0 = (f32x4)(0.f), a1 = (f32x4)(0.f);
    #pragma unroll
    for (int ks = 0; ks < NKS; ++ks) {
      a0 = __builtin_amdgcn_mfma_f32_16x16x32_bf16(af[ks], bA[ks], a0, 0, 0, 0);
      a1 = __builtin_amdgcn_mfma_f32_16x16x32_bf16(af[ks], bB[ks], a1, 0, 0, 0);
    }

    // Mask dead nodes at the store (alive <=> sel != 0).
    float al[4];
    #pragma unroll
    for (int r = 0; r < 4; ++r)
      al[r] = (s_sel[nt * 16 + q * 4 + r] != 0) ? 1.f : 0.f;

    // C/D: col = lane&15, row = (lane>>4)*4 + reg  [m89/m91]
    const long orow = base + nt * 16 + q * 4;
    #pragma unroll
    for (int r = 0; r < 4; ++r) {
      out[(orow + r) * OC + w * 16       + col] = a0[r] * al[r];
      out[(orow + r) * OC + (w + 4) * 16 + col] = a1[r] * al[r];
    }
  }
}

extern "C" void kernel_launch(void* const* d_in, const int* in_sizes, int n_in,
                              void* d_out, int out_size, void* d_ws, size_t ws_size,
                              hipStream_t stream) {
  const float* feat = (const float*)d_in[0];
  const float* w_s  = (const float*)d_in[1];
  const float* w_n  = (const float*)d_in[2];
  float* outp = (float*)d_out;
  ushort* wf = (ushort*)d_ws;  // 6*8*64*8 bf16 = 49152 bytes

  prep_w<<<dim3((NKS * 8 * 64 + 255) / 256), 256, 0, stream>>>(w_s, w_n, wf);
  rgc_v10<<<dim3(kNodes / NPB), THREADS, 0, stream>>>(feat, wf, outp);
}

// Round 11
// 79.430 us; speedup vs baseline: 1.8232x; 1.8232x over previous
//
#include <hip/hip_runtime.h>
#include <hip/hip_bf16.h>

// RuleGraphConvLayer R11 = R10 structure minus the spill:
// LDS holds the FINAL bf16 A-matrix (MFMA layout), built during staging;
// P3 is pure ds_read+MFMA with B fragments loaded per-ks from the global
// table (L1-hot, no cross-barrier register residency).
// K slots: [0..80] self(raw), [81..95] pad(B=0), [96..176] comb, [177..191] pad.
// Dead nodes (sel==0): cs=0 kills comb; self part masked at the store.
constexpr int kNodes = 262144;
constexpr int NC  = 103;   // feature columns
constexpr int F   = 81;    // used features
constexpr int OC  = 128;   // output channels
constexpr int NKS = 6;     // 6*32 = 192 K slots
constexpr int NPB = 64;    // nodes per block
constexpr int THREADS = 256;
constexpr int AST = 200;   // A-row stride in ushorts (400B)

typedef __attribute__((ext_vector_type(8))) short bf16x8;
typedef __attribute__((ext_vector_type(4))) float f32x4;

__device__ inline ushort f2bf(float f) {
  uint u = __float_as_uint(f);
  return (ushort)((u + 0x7fffu + ((u >> 16) & 1u)) >> 16);  // RNE
}
__device__ inline uint pk2(float a, float b) {
  ushort ua = __bfloat16_as_ushort(__float2bfloat16(a));
  ushort ub = __bfloat16_as_ushort(__float2bfloat16(b));
  return (uint)ua | ((uint)ub << 16);
}

// B table in fragment order: wf[ks][ct][lane] = 8 bf16.
// B[k][c]: k = ks*32 + (lane>>4)*8 + i, c = ct*16 + (lane&15).
// Rows: k<81 -> w_s[k]; 96<=k<177 -> w_n[k-96]; else 0.
__global__ __launch_bounds__(256)
void prep_w(const float* __restrict__ w_s, const float* __restrict__ w_n,
            ushort* __restrict__ wf) {
  int t = blockIdx.x * 256 + threadIdx.x;
  if (t >= NKS * 8 * 64) return;
  int l  = t & 63;
  int ct = (t >> 6) & 7;
  int ks = t >> 9;
  int c  = ct * 16 + (l & 15);
  int kb = ks * 32 + ((l >> 4) << 3);
  union { ushort u[8]; int4 v; } o;
  #pragma unroll
  for (int i = 0; i < 8; ++i) {
    int k = kb + i;
    float f = 0.f;
    if (k < F)                      f = w_s[k * OC + c];
    else if (k >= 96 && k < 96 + F) f = w_n[(k - 96) * OC + c];
    o.u[i] = f2bf(f);
  }
  ((int4*)wf)[t] = o.v;
}

__global__ __launch_bounds__(THREADS)
void rgc_v11(const float* __restrict__ feat, const ushort* __restrict__ wf,
             float* __restrict__ out) {
  __shared__ __align__(16) ushort a_bf[NPB * AST];  // 25600 B
  __shared__ int   s_sel[NPB];
  __shared__ float s_cs[NPB];

  const int tid = threadIdx.x;
  const int w   = tid >> 6;
  const int l   = tid & 63;
  const long base = (long)blockIdx.x * NPB;

  // ---- P1: self staging (raw bf16, slots [0..95]) + per-node meta.
  if (l < 16) {
    const int n = w * 16 + l;
    const float* row = feat + (base + n) * NC;
    float f0 = row[F], f1 = row[F + 1];
    int i0 = (int)f0, i1 = (int)f1;
    int sel = (i1 != 0) ? i1 : i0;          // alive <=> sel != 0
    const float* nr = feat + (long)sel * NC;
    float dx = row[0] - nr[0];
    float dy = row[1] - nr[1];
    float dz = row[2] - nr[2];
    float d2 = dx * dx + dy * dy + dz * dz;
    float alive = (sel != 0) ? 1.f : 0.f;
    s_sel[n] = sel;
    s_cs[n]  = alive * ((d2 > 0.f) ? (1.f / d2) : 10000.f);
  }
  #pragma unroll
  for (int j = 0; j < 12; ++j) {
    int v  = tid + j * THREADS;        // 0..3071
    int n  = v / 48;
    int kp = (v - n * 48) * 2;         // 0,2,..,94 (48 threads cover a row)
    const float* sr = feat + (base + n) * NC + kp;
    float x0 = sr[0], x1 = sr[1];
    *(uint*)&a_bf[n * AST + kp] = pk2(x0, x1);
  }
  __syncthreads();

  // ---- P2: comb staging (slots [96..191]); gather coalesced within rows.
  #pragma unroll
  for (int j = 0; j < 12; ++j) {
    int v  = tid + j * THREADS;
    int n  = v / 48;
    int kp = (v - n * 48) * 2;
    const float* nr = feat + (long)s_sel[n] * NC + kp;
    const float* sr = feat + (base + n) * NC + kp;   // L1/L2-hot (read in P1)
    float cs = s_cs[n];
    float nv0 = nr[0], nv1 = nr[1];
    float sv0 = sr[0], sv1 = sr[1];
    float y0 = (nv0 + ((kp     < 3) ? 0.f : sv0)) * cs;  // comb kk<3: nei only
    float y1 = (nv1 + ((kp + 1 < 3) ? 0.f : sv1)) * cs;
    *(uint*)&a_bf[n * AST + 96 + kp] = pk2(y0, y1);
  }
  __syncthreads();

  // ---- P3: pure MFMA. Wave w: 4 node-tiles x ct {w, w+4}.
  const int q    = l >> 4;
  const int lrow = l & 15;
  const int col  = l & 15;
  const bf16x8* wfv = (const bf16x8*)wf;

  #pragma unroll
  for (int nt = 0; nt < 4; ++nt) {
    const ushort* ap = a_bf + (nt * 16 + lrow) * AST + q * 8;
    bf16x8 af[NKS];
    #pragma unroll
    for (int ks = 0; ks < NKS; ++ks) af[ks] = *(const bf16x8*)(ap + ks * 32);

    f32x4 a0 = (f32x4)(0.f), a1 = (f32x4)(0.f);
    #pragma unroll
    for (int ks = 0; ks < NKS; ++ks) {
      bf16x8 bA = wfv[(ks * 8 + w)     * 64 + l];   // L1-hot after nt==0
      bf16x8 bB = wfv[(ks * 8 + w + 4) * 64 + l];
      a0 = __builtin_amdgcn_mfma_f32_16x16x32_bf16(af[ks], bA, a0, 0, 0, 0);
      a1 = __builtin_amdgcn_mfma_f32_16x16x32_bf16(af[ks], bB, a1, 0, 0, 0);
    }

    // Mask dead nodes at the store (alive <=> sel != 0).
    float al[4];
    #pragma unroll
    for (int r = 0; r < 4; ++r)
      al[r] = (s_sel[nt * 16 + q * 4 + r] != 0) ? 1.f : 0.f;

    // C/D: col = lane&15, row = (lane>>4)*4 + reg  [m89/m91]
    const long orow = base + nt * 16 + q * 4;
    #pragma unroll
    for (int r = 0; r < 4; ++r) {
      out[(orow + r) * OC + w * 16       + col] = a0[r] * al[r];
      out[(orow + r) * OC + (w + 4) * 16 + col] = a1[r] * al[r];
    }
  }
}

extern "C" void kernel_launch(void* const* d_in, const int* in_sizes, int n_in,
                              void* d_out, int out_size, void* d_ws, size_t ws_size,
                              hipStream_t stream) {
  const float* feat = (const float*)d_in[0];
  const float* w_s  = (const float*)d_in[1];
  const float* w_n  = (const float*)d_in[2];
  float* outp = (float*)d_out;
  ushort* wf = (ushort*)d_ws;  // 6*8*64*8 bf16 = 49152 bytes

  prep_w<<<dim3((NKS * 8 * 64 + 255) / 256), 256, 0, stream>>>(w_s, w_n, wf);
  rgc_v11<<<dim3(kNodes / NPB), THREADS, 0, stream>>>(feat, wf, outp);
}

// Round 12
// 75.111 us; speedup vs baseline: 1.9281x; 1.0575x over previous
//
#include <hip/hip_runtime.h>
#include <hip/hip_bf16.h>

// RuleGraphConvLayer R12 = R8 (champion) + 3 targeted fixes:
//  (1) meta (sel, 1/d^2) from global in P1, concurrent with copy: 4 -> 2 barriers
//  (2) NEI_STRIDE 100 -> 101 (5 mod 32, invertible): nei LDS reads 8-way -> 2-way
//  (3) all else identical to R8 (dumb staging, hoisted B, convert-in-compute)
// K slots: [0..80] self, [81..95] pad(B=0), [96..176] comb, [177..191] pad.
constexpr int kNodes = 262144;
constexpr int NC  = 103;   // feature columns
constexpr int F   = 81;    // used features
constexpr int OC  = 128;   // output channels
constexpr int NKS = 6;     // 6*32 = 192 K slots
constexpr int NPB = 64;    // nodes per block
constexpr int THREADS = 256;
constexpr int NEI_STRIDE = 101;  // 101 % 32 = 5 (odd, invertible) -> <=2-way banks
constexpr int GW = 96;           // dwords gathered per nei row

typedef __attribute__((ext_vector_type(8))) short bf16x8;
typedef __attribute__((ext_vector_type(4))) float f32x4;

__device__ inline ushort f2bf(float f) {
  uint u = __float_as_uint(f);
  return (ushort)((u + 0x7fffu + ((u >> 16) & 1u)) >> 16);  // RNE
}
__device__ inline short bfc(float x) {
  return (short)__bfloat16_as_ushort(__float2bfloat16(x));
}

// B table in fragment order: wf[ks][ct][lane] = 8 bf16.
// B[k][c]: k = ks*32 + (lane>>4)*8 + i, c = ct*16 + (lane&15).
// Rows: k<81 -> w_s[k]; 96<=k<177 -> w_n[k-96]; else 0.
__global__ __launch_bounds__(256)
void prep_w(const float* __restrict__ w_s, const float* __restrict__ w_n,
            ushort* __restrict__ wf) {
  int t = blockIdx.x * 256 + threadIdx.x;
  if (t >= NKS * 8 * 64) return;
  int l  = t & 63;
  int ct = (t >> 6) & 7;
  int ks = t >> 9;
  int c  = ct * 16 + (l & 15);
  int kb = ks * 32 + ((l >> 4) << 3);
  union { ushort u[8]; int4 v; } o;
  #pragma unroll
  for (int i = 0; i < 8; ++i) {
    int k = kb + i;
    float f = 0.f;
    if (k < F)                      f = w_s[k * OC + c];
    else if (k >= 96 && k < 96 + F) f = w_n[(k - 96) * OC + c];
    o.u[i] = f2bf(f);
  }
  ((int4*)wf)[t] = o.v;
}

__global__ __launch_bounds__(THREADS)
void rgc_v12(const float* __restrict__ feat, const ushort* __restrict__ wf,
             float* __restrict__ out) {
  __shared__ __align__(16) float lds_self[NPB * NC];          // 26368 B
  __shared__ __align__(16) float lds_nei[NPB * NEI_STRIDE];   // 25856 B
  __shared__ int   s_sel[NPB];
  __shared__ float s_cs[NPB];

  const int tid = threadIdx.x;
  const int w   = tid >> 6;
  const int l   = tid & 63;
  const long base = (long)blockIdx.x * NPB;
  const float* fbase = feat + base * NC;

  // ---- Hoisted B fragments: wave w owns ct = {w, w+4} (12 x 16B, once).
  const bf16x8* wfv = (const bf16x8*)wf;
  bf16x8 bA[NKS], bB[NKS];
  #pragma unroll
  for (int ks = 0; ks < NKS; ++ks) {
    bA[ks] = wfv[(ks * 8 + w)     * 64 + l];
    bB[ks] = wfv[(ks * 8 + w + 4) * 64 + l];
  }

  // ---- P1a: meta from GLOBAL, lanes 0..15 of wave w -> nodes w*16..w*16+15.
  // Runs concurrently with the copy below (independent loads).
  if (l < 16) {
    const int n = w * 16 + l;
    const float* row = feat + (base + n) * NC;
    float f0 = row[F], f1 = row[F + 1];
    int i0 = (int)f0, i1 = (int)f1;
    int sel = (i1 != 0) ? i1 : i0;            // alive <=> sel != 0
    const float* nr = feat + (long)sel * NC;
    float dx = row[0] - nr[0];
    float dy = row[1] - nr[1];
    float dz = row[2] - nr[2];
    float d2 = dx * dx + dy * dy + dz * dz;
    float alive = (sel != 0) ? 1.f : 0.f;
    s_sel[n] = sel;
    s_cs[n]  = alive * ((d2 > 0.f) ? (1.f / d2) : 10000.f);
  }

  // ---- P1b: raw self-row copy, fully coalesced float4 (1648 f4).
  {
    const float4* src = (const float4*)fbase;   // 64*103*4 % 16 == 0
    float4* dst = (float4*)lds_self;
    #pragma unroll
    for (int i = tid; i < NPB * NC / 4; i += THREADS) dst[i] = src[i];
  }
  __syncthreads();

  // ---- P2: nei gather, scalar dwords coalesced within rows (24 iters).
  #pragma unroll
  for (int j = 0; j < 24; ++j) {
    int v   = tid + j * THREADS;      // 0..6143
    int row = v / GW;
    int col = v - row * GW;
    lds_nei[row * NEI_STRIDE + col] = feat[(long)s_sel[row] * NC + col];
  }
  __syncthreads();

  // ---- P3: per wave, 4 node-tiles x 2 column tiles. A built from LDS,
  // B from VGPRs. Pad slots carry finite garbage x zero B rows.
  const int q    = l >> 4;
  const int lrow = l & 15;
  const int off0 = q * 8;
  const int col  = l & 15;

  #pragma unroll
  for (int nt = 0; nt < 4; ++nt) {
    const int n = nt * 16 + lrow;
    const float* sp = lds_self + n * NC;
    const float* np = lds_nei + n * NEI_STRIDE;
    const float alive = (s_sel[n] != 0) ? 1.f : 0.f;
    const float cs    = s_cs[n];

    bf16x8 afS[3], afC[3];
    #pragma unroll
    for (int c = 0; c < 3; ++c) {
      #pragma unroll
      for (int i = 0; i < 8; ++i) {
        float sv = sp[c * 32 + off0 + i];
        float nv = np[c * 32 + off0 + i];
        afS[c][i] = bfc(sv * alive);
        float se = sv;
        if (c == 0 && i < 3 && q == 0) se = 0.f;  // comb kk<3: nei coords only
        afC[c][i] = bfc((nv + se) * cs);
      }
    }

    f32x4 a0 = (f32x4)(0.f), a1 = (f32x4)(0.f);
    #pragma unroll
    for (int ks = 0; ks < NKS; ++ks) {
      bf16x8 af = (ks < 3) ? afS[ks] : afC[ks - 3];
      a0 = __builtin_amdgcn_mfma_f32_16x16x32_bf16(af, bA[ks], a0, 0, 0, 0);
      a1 = __builtin_amdgcn_mfma_f32_16x16x32_bf16(af, bB[ks], a1, 0, 0, 0);
    }

    // C/D: col = lane&15, row = (lane>>4)*4 + reg  [m89/m91]
    // Each store instr: 4 rows x one full 64B line -> clean write-combining.
    const long orow = base + nt * 16 + q * 4;
    #pragma unroll
    for (int r = 0; r < 4; ++r) {
      out[(orow + r) * OC + w * 16       + col] = a0[r];
      out[(orow + r) * OC + (w + 4) * 16 + col] = a1[r];
    }
  }
}

extern "C" void kernel_launch(void* const* d_in, const int* in_sizes, int n_in,
                              void* d_out, int out_size, void* d_ws, size_t ws_size,
                              hipStream_t stream) {
  const float* feat = (const float*)d_in[0];
  const float* w_s  = (const float*)d_in[1];
  const float* w_n  = (const float*)d_in[2];
  float* outp = (float*)d_out;
  ushort* wf = (ushort*)d_ws;  // 6*8*64*8 bf16 = 49152 bytes

  prep_w<<<dim3((NKS * 8 * 64 + 255) / 256), 256, 0, stream>>>(w_s, w_n, wf);
  rgc_v12<<<dim3(kNodes / NPB), THREADS, 0, stream>>>(feat, wf, outp);
}

// Round 13
// 67.753 us; speedup vs baseline: 2.1374x; 1.1086x over previous
//
#include <hip/hip_runtime.h>
#include <hip/hip_bf16.h>

// RuleGraphConvLayer R13 = R8 structure with all staging via
// global_load_lds (zero-VGPR async DMA), XOR-swizzled nei layout.
// K slots: [0..80] self, [81..95] pad(B=0), [96..176] comb, [177..191] pad.
constexpr int kNodes = 262144;
constexpr int NC  = 103;   // feature columns
constexpr int F   = 81;    // used features
constexpr int OC  = 128;   // output channels
constexpr int NKS = 6;     // 6*32 = 192 K slots
constexpr int NPB = 64;    // nodes per block
constexpr int THREADS = 256;
constexpr int NST = 96;    // nei LDS row stride (dwords) -> gll dest linear
constexpr int SELF_F4 = NPB * NC / 4;  // 1648

typedef __attribute__((ext_vector_type(8))) short bf16x8;
typedef __attribute__((ext_vector_type(4))) float f32x4;

__device__ inline ushort f2bf(float f) {
  uint u = __float_as_uint(f);
  return (ushort)((u + 0x7fffu + ((u >> 16) & 1u)) >> 16);  // RNE
}
__device__ inline short bfc(float x) {
  return (short)__bfloat16_as_ushort(__float2bfloat16(x));
}

__device__ __forceinline__ void gll4(const float* g, float* l) {
  __builtin_amdgcn_global_load_lds(
      (const __attribute__((address_space(1))) unsigned int*)g,
      (__attribute__((address_space(3))) unsigned int*)l, 4, 0, 0);
}
__device__ __forceinline__ void gll16(const float* g, float* l) {
  __builtin_amdgcn_global_load_lds(
      (const __attribute__((address_space(1))) unsigned int*)g,
      (__attribute__((address_space(3))) unsigned int*)l, 16, 0, 0);
}

// B table in fragment order: wf[ks][ct][lane] = 8 bf16.
// B[k][c]: k = ks*32 + (lane>>4)*8 + i, c = ct*16 + (lane&15).
// Rows: k<81 -> w_s[k]; 96<=k<177 -> w_n[k-96]; else 0.
__global__ __launch_bounds__(256)
void prep_w(const float* __restrict__ w_s, const float* __restrict__ w_n,
            ushort* __restrict__ wf) {
  int t = blockIdx.x * 256 + threadIdx.x;
  if (t >= NKS * 8 * 64) return;
  int l  = t & 63;
  int ct = (t >> 6) & 7;
  int ks = t >> 9;
  int c  = ct * 16 + (l & 15);
  int kb = ks * 32 + ((l >> 4) << 3);
  union { ushort u[8]; int4 v; } o;
  #pragma unroll
  for (int i = 0; i < 8; ++i) {
    int k = kb + i;
    float f = 0.f;
    if (k < F)                      f = w_s[k * OC + c];
    else if (k >= 96 && k < 96 + F) f = w_n[(k - 96) * OC + c];
    o.u[i] = f2bf(f);
  }
  ((int4*)wf)[t] = o.v;
}

__global__ __launch_bounds__(THREADS)
void rgc_v13(const float* __restrict__ feat, const ushort* __restrict__ wf,
             float* __restrict__ out) {
  __shared__ __align__(16) float lds_self[NPB * NC];   // 26368 B (stride 103)
  __shared__ __align__(16) float lds_nei[NPB * NST];   // 24576 B (stride 96, swz)
  __shared__ int   s_sel[NPB];
  __shared__ float s_cs[NPB];

  const int tid = threadIdx.x;
  const int w   = tid >> 6;
  const int l   = tid & 63;
  const long base = (long)blockIdx.x * NPB;
  const float* fbase = feat + base * NC;

  // ---- Hoisted B fragments (compiler schedules/remats as it likes).
  const bf16x8* wfv = (const bf16x8*)wf;
  bf16x8 bA[NKS], bB[NKS];
  #pragma unroll
  for (int ks = 0; ks < NKS; ++ks) {
    bA[ks] = wfv[(ks * 8 + w)     * 64 + l];
    bB[ks] = wfv[(ks * 8 + w + 4) * 64 + l];
  }

  // ---- P0: fire self-copy DMA (stays in flight across the barrier),
  // and resolve sel per node (lanes 0..15 of wave w -> nodes w*16+l).
  #pragma unroll
  for (int j = 0; j < 7; ++j) {
    int i = tid + j * THREADS;              // f4 index
    if (j < 6 || i < SELF_F4) {
      gll16((const float*)((const float4*)fbase + i),
            (float*)((float4*)lds_self + (j * THREADS + w * 64)));
    }
  }
  if (l < 16) {
    const int n = w * 16 + l;
    const float* row = feat + (base + n) * NC;
    float f0 = row[F], f1 = row[F + 1];
    int i0 = (int)f0, i1 = (int)f1;
    s_sel[n] = (i1 != 0) ? i1 : i0;         // alive <=> sel != 0
  }
  asm volatile("s_waitcnt lgkmcnt(0)" ::: "memory");  // sel visible, DMA still flying
  __builtin_amdgcn_s_barrier();

  // ---- P1: nei gather DMA. LDS dword v holds logical col with 16B-chunk
  // XOR swizzle: within each 32-dword group, chunk x stores logical chunk
  // x ^ (row & 7). Source address carries the swizzle (involution).
  #pragma unroll
  for (int j = 0; j < 24; ++j) {
    int v   = tid + j * THREADS;            // 0..6143
    int row = v / NST;
    int p   = v - row * NST;
    int c   = p >> 5;
    int x   = (p >> 2) & 7;
    int cl  = p & 3;
    int col = (c << 5) + ((x ^ (row & 7)) << 2) + cl;
    gll4(feat + (long)s_sel[row] * NC + col,
         lds_nei + (j * THREADS + w * 64));
  }
  asm volatile("s_waitcnt vmcnt(0) lgkmcnt(0)" ::: "memory");  // all LDS data landed
  __builtin_amdgcn_s_barrier();

  // ---- P2: 1/d^2 from LDS-staged coords (full f32 precision).
  if (tid < NPB) {
    const int n = tid;
    const int r = n & 7;
    // nei coords: logical cols 0..2 live at chunk (0 ^ r) -> dwords r*4+cl.
    float nx = lds_nei[n * NST + r * 4 + 0];
    float ny = lds_nei[n * NST + r * 4 + 1];
    float nz = lds_nei[n * NST + r * 4 + 2];
    float dx = lds_self[n * NC + 0] - nx;
    float dy = lds_self[n * NC + 1] - ny;
    float dz = lds_self[n * NC + 2] - nz;
    float d2 = dx * dx + dy * dy + dz * dz;
    float alive = (s_sel[n] != 0) ? 1.f : 0.f;
    s_cs[n] = alive * ((d2 > 0.f) ? (1.f / d2) : 10000.f);
  }
  asm volatile("s_waitcnt lgkmcnt(0)" ::: "memory");
  __builtin_amdgcn_s_barrier();

  // ---- P3: per wave, 4 node-tiles x 2 column tiles (identical math to R8).
  const int q    = l >> 4;
  const int lrow = l & 15;
  const int off0 = q * 8;
  const int col  = l & 15;

  #pragma unroll
  for (int nt = 0; nt < 4; ++nt) {
    const int n = nt * 16 + lrow;
    const int r = n & 7;
    const float* sp = lds_self + n * NC;
    const float* np = lds_nei + n * NST;
    const float alive = (s_sel[n] != 0) ? 1.f : 0.f;
    const float cs    = s_cs[n];

    bf16x8 afS[3], afC[3];
    #pragma unroll
    for (int c = 0; c < 3; ++c) {
      // logical dwords c*32 + q*8 .. +7 = swizzled chunks (2q)^r, (2q+1)^r
      f32x4 lo = *(const f32x4*)(np + c * 32 + (((2 * q)     ^ r) << 2));
      f32x4 hi = *(const f32x4*)(np + c * 32 + (((2 * q + 1) ^ r) << 2));
      #pragma unroll
      for (int i = 0; i < 8; ++i) {
        float sv = sp[c * 32 + off0 + i];
        float nv = (i < 4) ? lo[i] : hi[i - 4];
        afS[c][i] = bfc(sv * alive);
        float se = sv;
        if (c == 0 && i < 3 && q == 0) se = 0.f;  // comb kk<3: nei coords only
        afC[c][i] = bfc((nv + se) * cs);
      }
    }

    f32x4 a0 = (f32x4)(0.f), a1 = (f32x4)(0.f);
    #pragma unroll
    for (int ks = 0; ks < NKS; ++ks) {
      bf16x8 af = (ks < 3) ? afS[ks] : afC[ks - 3];
      a0 = __builtin_amdgcn_mfma_f32_16x16x32_bf16(af, bA[ks], a0, 0, 0, 0);
      a1 = __builtin_amdgcn_mfma_f32_16x16x32_bf16(af, bB[ks], a1, 0, 0, 0);
    }

    // C/D: col = lane&15, row = (lane>>4)*4 + reg  [m89/m91]
    const long orow = base + nt * 16 + q * 4;
    #pragma unroll
    for (int rr = 0; rr < 4; ++rr) {
      out[(orow + rr) * OC + w * 16       + col] = a0[rr];
      out[(orow + rr) * OC + (w + 4) * 16 + col] = a1[rr];
    }
  }
}

extern "C" void kernel_launch(void* const* d_in, const int* in_sizes, int n_in,
                              void* d_out, int out_size, void* d_ws, size_t ws_size,
                              hipStream_t stream) {
  const float* feat = (const float*)d_in[0];
  const float* w_s  = (const float*)d_in[1];
  const float* w_n  = (const float*)d_in[2];
  float* outp = (float*)d_out;
  ushort* wf = (ushort*)d_ws;  // 6*8*64*8 bf16 = 49152 bytes

  prep_w<<<dim3((NKS * 8 * 64 + 255) / 256), 256, 0, stream>>>(w_s, w_n, wf);
  rgc_v13<<<dim3(kNodes / NPB), THREADS, 0, stream>>>(feat, wf, outp);
}